// Round 8
// baseline (184.637 us; speedup 1.0000x reference)
//
#include <hip/hip_runtime.h>

#define BLK   512
#define NSAMP 8
#define REG   1480          // dwords per sample LDS region (5920 B)
#define GRID  768           // 3 persistent blocks per CU (256 CUs)
// per-sample region map (R8 — P2/P3 moved INTO the dead P1 region so IMG stays
// free for concurrent restaging of the next group):
//  IMG: halfwords [0..783] = dw [0..391]  — read by conv1 only; restaged in overlap
//  W:   dw [392..1203] (811 hypernet weights, fp32, PERMUTED — see below)
//  P1:  halfwords [2408..2953] = dw [1204..1476] — written conv1, read conv2
//  P2:  dw [1204..1353] — ALIASES P1 head; conv2 stores AFTER all P1 reads (ordered)
//  P3:  dw [1364..1390] — aliases P1 tail (dead after conv2); spatial-major pos*3+c
#define OFF_W    392
#define HW_P1    2408
#define DW_P1    1204
#define DW_P2    1204
#define DW_P3    1364

typedef short bf16x8 __attribute__((ext_vector_type(8)));
typedef float f32x4  __attribute__((ext_vector_type(4)));
typedef float f32x2  __attribute__((ext_vector_type(2)));

// Journal:
// R1: asm v_pk_fma op_sel broadcast FAILED correctness. Never again.
// R2 (proven 65us): C float2 packed math — compiler emits v_pk_fma, exact.
// R3 (REGRESSED): bf16 W in LDS -> merge-proof ds_read_u16. Occupancy not binding.
// R5 (NEUTRAL): W3 reg-prefetch sunk by compiler. R6 (REGRESSED): pinning it
//   fenced the staging loads — never fence before the dominant memory phase.
// R7 (= baseline 66us): s_pj table + v_perm staging proven correct, ~neutral.
// R8: persistent blocks + software pipeline — stage(g+1)+MLP(g+1) overlap
//   conv2-4(g). LDS re-layout (P2/P3 into P1) frees IMG for concurrent restage;
//   zero LDS growth; math untouched (absmax must stay exactly 0.5).

__device__ __forceinline__ float bf2f(unsigned short u) {
    return __uint_as_float(((unsigned int)u) << 16);
}
__device__ __forceinline__ unsigned short f2bf(float f) {
    unsigned int x = __float_as_uint(f);
    return (unsigned short)((x + 0x7fffu + ((x >> 16) & 1u)) >> 16);   // RNE
}
__device__ __forceinline__ void wsync() {
    __builtin_amdgcn_wave_barrier();
    __asm__ volatile("s_waitcnt lgkmcnt(0)" ::: "memory");
    __builtin_amdgcn_wave_barrier();
}

__device__ __forceinline__ bool is_bf16(const void* p, int elems) {
    const unsigned short* h = (const unsigned short*)p;
    int n = elems; if (n > 32) n = 32;
    int nz = 0, ok = 0;
    for (int i = 0; i < n; i += 2) {
        unsigned short u = h[i];
        if (u == 0) continue;
        ++nz;
        unsigned int e = (u >> 7) & 255u;
        if (e >= 100u && e <= 141u) ++ok;
    }
    if (nz < 4) return true;
    return 4 * ok >= 3 * nz;
}

// head-write permutation: logical j -> stored index
__device__ __forceinline__ int wperm(int j) {
    if (j >= 30 && j < 192) {
        int rel = j - 30, c = rel / 27, r2 = rel - 27 * c;
        int tap = r2 / 3, ci = r2 - 3 * tap;
        return 30 + c * 27 + ci * 9 + tap;
    }
    if (j >= 198 && j < 360) {
        int rel = j - 198, c = rel / 54, r3 = rel - 54 * c;
        int tap = r3 / 6, ci = r3 - 6 * tap;
        return 198 + c * 54 + ci * 9 + tap;
    }
    return j;
}

// ---- phase helpers (wave-role code shared by prologue and pipeline loop) ----

__device__ __forceinline__ void do_stage(const void* image, float* SH, int B,
                                         int b0, int t, bool im_bf)
{
    unsigned short* su = (unsigned short*)SH;
    if (im_bf) {
        const unsigned short* im = (const unsigned short*)image;
        unsigned* sd = (unsigned*)SH;
        int d = t - 128;               // 0..383
        {
            const uint4 v0 = *(const uint4*)(im + (2 * d)     * B + b0);
            const uint4 v1 = *(const uint4*)(im + (2 * d + 1) * B + b0);
            unsigned a0[4] = {v0.x, v0.y, v0.z, v0.w};
            unsigned a1[4] = {v1.x, v1.y, v1.z, v1.w};
#pragma unroll
            for (int s = 0; s < 8; ++s) {
                unsigned m = __builtin_amdgcn_perm(
                    a1[s >> 1], a0[s >> 1],
                    (s & 1) ? 0x07060302u : 0x05040100u);
                sd[s * REG + d] = m;
            }
        }
        if (d < 8) {                   // dwords 384..391
            const int d2 = d + 384;
            const uint4 v0 = *(const uint4*)(im + (2 * d2)     * B + b0);
            const uint4 v1 = *(const uint4*)(im + (2 * d2 + 1) * B + b0);
            unsigned a0[4] = {v0.x, v0.y, v0.z, v0.w};
            unsigned a1[4] = {v1.x, v1.y, v1.z, v1.w};
#pragma unroll
            for (int s = 0; s < 8; ++s) {
                unsigned m = __builtin_amdgcn_perm(
                    a1[s >> 1], a0[s >> 1],
                    (s & 1) ? 0x07060302u : 0x05040100u);
                sd[s * REG + d2] = m;
            }
        }
    } else {
        const float* im = (const float*)image;
        int pix0 = t - 128;            // 0..383
        for (int pix = pix0; pix < 784; pix += 384) {
            const float4 a = *(const float4*)(im + pix * B + b0);
            const float4 c = *(const float4*)(im + pix * B + b0 + 4);
            su[0 * 2 * REG + pix] = f2bf(a.x);
            su[1 * 2 * REG + pix] = f2bf(a.y);
            su[2 * 2 * REG + pix] = f2bf(a.z);
            su[3 * 2 * REG + pix] = f2bf(a.w);
            su[4 * 2 * REG + pix] = f2bf(c.x);
            su[5 * 2 * REG + pix] = f2bf(c.y);
            su[6 * 2 * REG + pix] = f2bf(c.z);
            su[7 * 2 * REG + pix] = f2bf(c.w);
        }
    }
}

__device__ __forceinline__ void do_mlp(const void* state,
                                       const void* W1, const void* b1,
                                       const void* W2, const void* b2,
                                       float (*st)[16], float (*h1)[16], float (*h2)[16],
                                       int b0, int wv, int lane,
                                       bool st_bf, bool w1_bf, bool b1_bf,
                                       bool w2_bf, bool b2_bf)
{
    int s = wv * 4 + (lane >> 4), j = lane & 15;
    int gi = (b0 + s) * 16 + j;
    st[s][j] = st_bf ? bf2f(((const unsigned short*)state)[gi])
                     : ((const float*)state)[gi];
    wsync();
    float acc = b1_bf ? bf2f(((const unsigned short*)b1)[j])
                      : ((const float*)b1)[j];
#pragma unroll
    for (int k = 0; k < 16; ++k) {
        float w = w1_bf ? bf2f(((const unsigned short*)W1)[k * 16 + j])
                        : ((const float*)W1)[k * 16 + j];
        acc += st[s][k] * w;
    }
    h1[s][j] = fmaxf(acc, 0.f);
    wsync();
    acc = b2_bf ? bf2f(((const unsigned short*)b2)[j])
                : ((const float*)b2)[j];
#pragma unroll
    for (int k = 0; k < 16; ++k) {
        float w = w2_bf ? bf2f(((const unsigned short*)W2)[k * 16 + j])
                        : ((const float*)W2)[k * 16 + j];
        acc += h1[s][k] * w;
    }
    h2[s][j] = fmaxf(acc, 0.f);
}

// head via MFMA: W[8][811] = h2[8][16] @ W3[16][811] + b3 (R2-proven dynamic loop)
__device__ __forceinline__ void do_head(const void* W3, const void* b3,
                                        float* SH, float (*h2)[16],
                                        const unsigned short* s_pj,
                                        int wv, int hn, int kg,
                                        bool w3_bf, bool b3_bf)
{
    bf16x8 afrag;
#pragma unroll
    for (int i = 0; i < 8; ++i) afrag[i] = 0;
    if (kg < 2 && hn < 8) {
        const int k0 = kg * 8;
#pragma unroll
        for (int i = 0; i < 8; ++i)
            afrag[i] = (short)f2bf(h2[hn][k0 + i]);
    }
    const unsigned short* b3h = (const unsigned short*)b3;
    const float*          b3f = (const float*)b3;
    for (int tile = wv; tile < 51; tile += 8) {
        const int jn = tile * 16 + hn;
        bf16x8 bfrag;
#pragma unroll
        for (int i = 0; i < 8; ++i) bfrag[i] = 0;
        if (kg < 2 && jn < 811) {
            const int k0 = kg * 8;
            if (w3_bf) {
                const unsigned short* q = (const unsigned short*)W3 + k0 * 811 + jn;
#pragma unroll
                for (int i = 0; i < 8; ++i) bfrag[i] = (short)q[i * 811];
            } else {
                const float* q = (const float*)W3 + k0 * 811 + jn;
#pragma unroll
                for (int i = 0; i < 8; ++i) bfrag[i] = (short)f2bf(q[i * 811]);
            }
        }
        f32x4 c = {0.f, 0.f, 0.f, 0.f};
        c = __builtin_amdgcn_mfma_f32_16x16x32_bf16(afrag, bfrag, c, 0, 0, 0);
        const int row0 = kg * 4;
        if (row0 < 8 && jn < 811) {
            float bb = b3_bf ? bf2f(b3h[jn]) : b3f[jn];
            const int pj = (int)s_pj[jn];
#pragma unroll
            for (int r = 0; r < 4; ++r)
                SH[(row0 + r) * REG + OFF_W + pj] = c[r] + bb;
        }
    }
}

// bound (512,4): VGPR cap 128. Must stay <=64 VGPR to keep 8 waves/SIMD possible
// (LDS caps at 3 blocks/CU = 6 waves/SIMD). NO runtime-indexed ext_vector arrays.
__global__ __launch_bounds__(BLK, 4)
void dyncnn4_kernel(const void* __restrict__ image,   // [784, B]
                    const void* __restrict__ state,   // [B, 16]
                    const void* __restrict__ W1, const void* __restrict__ b1,
                    const void* __restrict__ W2, const void* __restrict__ b2,
                    const void* __restrict__ W3, const void* __restrict__ b3,
                    void* __restrict__ out,           // [B,16]
                    int B, int ngrp, int nswz)
{
    __shared__ float SH[NSAMP * REG];     // 47360 B
    __shared__ float s_st[2][NSAMP][16];  // double-buffered (pipeline)
    __shared__ float s_h1[NSAMP][16];
    __shared__ float s_h2[NSAMP][16];
    __shared__ unsigned char s_fl[8];
    __shared__ unsigned short s_pj[812];

    const int t    = threadIdx.x;
    const int wv   = t >> 6;
    const int lane = t & 63;
    const int hn   = lane & 15;
    const int kg   = lane >> 4;

    // ---- barrier #0: dtype flags + wperm table (once per block) ----
    if (t < 8) {
        const void* q; int n;
        switch (t) {
            case 0:  q = image; n = 784 * B; break;
            case 1:  q = state; n = 16 * B;  break;
            case 2:  q = W1;    n = 256;     break;
            case 3:  q = b1;    n = 16;      break;
            case 4:  q = W2;    n = 256;     break;
            case 5:  q = b2;    n = 16;      break;
            case 6:  q = W3;    n = 12976;   break;
            default: q = b3;    n = 811;     break;
        }
        s_fl[t] = is_bf16(q, n) ? 1 : 0;
    }
    for (int j = t; j < 811; j += BLK)
        s_pj[j] = (unsigned short)wperm(j);
    __syncthreads();
    const bool im_bf = s_fl[0], st_bf = s_fl[1], w1_bf = s_fl[2], b1_bf = s_fl[3];
    const bool w2_bf = s_fl[4], b2_bf = s_fl[5], w3_bf = s_fl[6], b3_bf = s_fl[7];
    const bool out_bf = im_bf && st_bf && w1_bf && w2_bf && w3_bf;

    int g = blockIdx.x;
    if (g >= ngrp) return;
    const int stride = gridDim.x;

    // group -> sample-base (XCD swizzle preserved)
    int lg = (nswz > 0) ? ((g & 7) * nswz + (g >> 3)) : g;
    int b0 = lg * NSAMP;

    unsigned short* su = (unsigned short*)SH;

    // ==== prologue: stage(g0) + MLP(g0) -> head(g0) ====
    if (wv < 2) do_mlp(state, W1, b1, W2, b2, s_st[0], s_h1, s_h2, b0, wv, lane,
                       st_bf, w1_bf, b1_bf, w2_bf, b2_bf);
    else        do_stage(image, SH, B, b0, t, im_bf);
    __syncthreads();                      // image + h2 ready
    do_head(W3, b3, SH, s_h2, s_pj, wv, hn, kg, w3_bf, b3_bf);
    __syncthreads();                      // W ready

    int buf = 0;
    for (;;) {
        const int sb  = wv * REG;
        const int sb2 = wv * 2 * REG;

        // ---- conv1 (1->3, 28x28 -> pool -> 13x13x3 bf16), C-packed f32 ----
        {
            float wc[27], cb[3];
#pragma unroll
            for (int i = 0; i < 27; ++i) wc[i] = SH[sb + OFF_W + i];
#pragma unroll
            for (int c = 0; c < 3; ++c) cb[c] = SH[sb + OFF_W + 27 + c];
            const unsigned* suw = (const unsigned*)&SH[sb];
#pragma unroll
            for (int it = 0; it < 3; ++it) {
                int pix = lane + it * 64;
                if (pix < 169) {
                    int py = pix / 13, px = pix - py * 13;
                    int iy = 2 * py;
                    f32x2 P[4][3];
#pragma unroll
                    for (int dy = 0; dy < 4; ++dy) {
                        int r = (iy + dy) * 14 + px;
                        unsigned d0 = suw[r], d1 = suw[r + 1];
                        float c0 = __uint_as_float(d0 << 16);
                        float c1 = __uint_as_float(d0 & 0xffff0000u);
                        float c2 = __uint_as_float(d1 << 16);
                        float c3 = __uint_as_float(d1 & 0xffff0000u);
                        P[dy][0] = (f32x2){c0, c1};
                        P[dy][1] = (f32x2){c1, c2};
                        P[dy][2] = (f32x2){c2, c3};
                    }
                    unsigned short* op = &su[sb2 + HW_P1 + py * 14 + px];
#pragma unroll
                    for (int c = 0; c < 3; ++c) {
                        f32x2 at = {0.f, 0.f}, ab = {0.f, 0.f};
#pragma unroll
                        for (int ky = 0; ky < 3; ++ky)
#pragma unroll
                            for (int kx = 0; kx < 3; ++kx) {
                                float w = wc[c * 9 + ky * 3 + kx];
                                f32x2 ws = {w, w};
                                at += P[ky][kx]     * ws;
                                ab += P[ky + 1][kx] * ws;
                            }
                        float m = fmaxf(fmaxf(at.x, at.y), fmaxf(ab.x, ab.y));
                        op[c * 182] = f2bf(fmaxf(m + cb[c], 0.f));
                    }
                }
            }
        }
        __syncthreads();                  // barA: IMG(g) fully consumed

        // ---- overlap region: stage/MLP of next group runs alongside conv2-4 ----
        int gn = g + stride;
        bool more = (gn < ngrp);
        int b0n = 0;
        if (more) {
            int lgn = (nswz > 0) ? ((gn & 7) * nswz + (gn >> 3)) : gn;
            b0n = lgn * NSAMP;
            if (wv < 2) do_mlp(state, W1, b1, W2, b2, s_st[buf ^ 1], s_h1, s_h2,
                               b0n, wv, lane, st_bf, w1_bf, b1_bf, w2_bf, b2_bf);
            else        do_stage(image, SH, B, b0n, t, im_bf);
        }

        // ---- conv2 (3->6 -> pool -> 5x5x6 fp32), ci-outer, C-packed ----
        // reads P1 (all reads precede P2 stores; P2 aliases P1 head — ordered)
        {
            int gq = lane >> 5, q = lane & 31;
            if (q < 25) {
                int py = q / 5, px = q - py * 5;
                const unsigned* p1w = (const unsigned*)&SH[sb + DW_P1];
                f32x2 aT0 = {0.f,0.f}, aB0 = {0.f,0.f};
                f32x2 aT1 = {0.f,0.f}, aB1 = {0.f,0.f};
                f32x2 aT2 = {0.f,0.f}, aB2 = {0.f,0.f};
#pragma unroll
                for (int ci = 0; ci < 3; ++ci) {
                    f32x2 P[4][3];
#pragma unroll
                    for (int dy = 0; dy < 4; ++dy) {
                        int r = ci * 91 + (2 * py + dy) * 7 + px;
                        unsigned d0 = p1w[r], d1 = p1w[r + 1];
                        float c0 = __uint_as_float(d0 << 16);
                        float c1 = __uint_as_float(d0 & 0xffff0000u);
                        float c2 = __uint_as_float(d1 << 16);
                        float c3 = __uint_as_float(d1 & 0xffff0000u);
                        P[dy][0] = (f32x2){c0, c1};
                        P[dy][1] = (f32x2){c1, c2};
                        P[dy][2] = (f32x2){c2, c3};
                    }
#pragma unroll
                    for (int it = 0; it < 3; ++it) {
                        int c = it * 2 + gq;
                        const int wo = sb + OFF_W + 30 + c * 27 + ci * 9;
#pragma unroll
                        for (int ky = 0; ky < 3; ++ky)
#pragma unroll
                            for (int kx = 0; kx < 3; ++kx) {
                                float w = SH[wo + ky * 3 + kx];
                                f32x2 ws = {w, w};
                                if (it == 0) { aT0 += P[ky][kx] * ws; aB0 += P[ky+1][kx] * ws; }
                                if (it == 1) { aT1 += P[ky][kx] * ws; aB1 += P[ky+1][kx] * ws; }
                                if (it == 2) { aT2 += P[ky][kx] * ws; aB2 += P[ky+1][kx] * ws; }
                            }
                    }
                }
#pragma unroll
                for (int it = 0; it < 3; ++it) {
                    int c = it * 2 + gq;
                    f32x2 aT = (it == 0) ? aT0 : (it == 1) ? aT1 : aT2;
                    f32x2 aB = (it == 0) ? aB0 : (it == 1) ? aB1 : aB2;
                    float m = fmaxf(fmaxf(aT.x, aT.y), fmaxf(aB.x, aB.y));
                    SH[sb + DW_P2 + c * 25 + q] =
                        fmaxf(m + SH[sb + OFF_W + 192 + c], 0.f);
                }
            }
        }
        wsync();

        // ---- conv3 (6->3, 5x5 -> 3x3) + relu; P3 spatial-major in P1 tail ----
        {
            float acc = 0.f;
            int pq = lane % 27;
            int half = lane / 27;
            int c = pq / 9, pos = pq - c * 9;
            int py = pos / 3, px = pos - py * 3;
            if (lane < 54) {
                const int cb3 = half * 3;
#pragma unroll
                for (int ci3 = 0; ci3 < 3; ++ci3) {
                    const int ci = cb3 + ci3;
                    const int wo = sb + OFF_W + 198 + c * 54 + ci * 9;
                    float wr[9];
#pragma unroll
                    for (int i = 0; i < 9; ++i) wr[i] = SH[wo + i];
                    const int pbase = sb + DW_P2 + ci * 25 + py * 5 + px;
#pragma unroll
                    for (int ky = 0; ky < 3; ++ky)
#pragma unroll
                        for (int kx = 0; kx < 3; ++kx)
                            acc += SH[pbase + ky * 5 + kx] * wr[ky * 3 + kx];
                }
            }
            float other = __shfl(acc, (lane + 27) & 63);
            if (lane < 27)
                SH[sb + DW_P3 + pos * 3 + c] =
                    fmaxf(acc + other + SH[sb + OFF_W + 360 + c], 0.f);
        }
        wsync();

        // ---- conv4 (3->16) + bias + residual -> out ----
        {
            float acc = 0.f;
            int os = lane & 15, h = (lane >> 4) & 1;
            if (lane < 32) {
                const int wo = sb + OFF_W + 363 + os * 27;
                int p0 = h ? 4 : 0, p1 = h ? 9 : 4;
                for (int pp = p0; pp < p1; ++pp)
#pragma unroll
                    for (int ci = 0; ci < 3; ++ci)
                        acc += SH[sb + DW_P3 + pp * 3 + ci] * SH[wo + pp * 3 + ci];
            }
            float other = __shfl(acc, (lane + 16) & 63);
            if (lane < 16) {
                float tot = acc + other + SH[sb + OFF_W + 795 + os]
                          + s_st[buf][wv][os];
                int gi = (b0 + wv) * 16 + os;
                if (out_bf) ((unsigned short*)out)[gi] = f2bf(tot);
                else        ((float*)out)[gi] = tot;
            }
        }
        __syncthreads();                  // barB: convs(g) done, stage/MLP(gn) done

        if (!more) break;
        do_head(W3, b3, SH, s_h2, s_pj, wv, hn, kg, w3_bf, b3_bf);  // W(gn)
        __syncthreads();                  // barC: W(gn) ready
        g = gn; b0 = b0n; buf ^= 1;
    }
}

extern "C" void kernel_launch(void* const* d_in, const int* in_sizes, int n_in,
                              void* d_out, int out_size, void* d_ws, size_t ws_size,
                              hipStream_t stream) {
    (void)d_ws; (void)ws_size; (void)n_in; (void)out_size;
    int B = in_sizes[1] / 16;              // 16384
    int ngrp = B / NSAMP;                  // 2048
    int nswz = (ngrp % 8 == 0) ? (ngrp / 8) : 0;
    int grid = (ngrp < GRID) ? ngrp : GRID;

    dyncnn4_kernel<<<grid, BLK, 0, stream>>>(
        d_in[0], d_in[1], d_in[2], d_in[3], d_in[4], d_in[5], d_in[6], d_in[7],
        d_out, B, ngrp, nswz);
}

// Round 9
// 145.339 us; speedup vs baseline: 1.2704x; 1.2704x over previous
//
#include <hip/hip_runtime.h>

#define BLK   512
#define NSAMP 8
#define REG   1480          // dwords per sample LDS region (5920 B)
// per-sample region map (R8-proven layout — P2/P3 INSIDE dead P1 so IMG stays
// free for concurrent restaging of the next group):
//  IMG: halfwords [0..783] = dw [0..391]  — read by conv1 only
//  W:   dw [392..1203] (811 hypernet weights, fp32, PERMUTED)
//  P1:  halfwords [2408..2953] = dw [1204..1476] — written conv1, read conv2
//  P2:  dw [1204..1353] — aliases P1 head; conv2 stores after all P1 reads
//  P3:  dw [1364..1390] — aliases P1 tail (dead after conv2); pos*3+c
#define OFF_W    392
#define HW_P1    2408
#define DW_P1    1204
#define DW_P2    1204
#define DW_P3    1364

typedef short bf16x8 __attribute__((ext_vector_type(8)));
typedef float f32x4  __attribute__((ext_vector_type(4)));
typedef float f32x2  __attribute__((ext_vector_type(2)));

// Journal:
// R1: asm v_pk_fma op_sel broadcast FAILED correctness. Never again.
// R2 (proven 65us): C float2 packed math — compiler emits v_pk_fma, exact.
// R3 (REGRESSED): bf16 W in LDS -> merge-proof ds_read_u16.
// R6 (REGRESSED): fencing W3 prefetch stalled staging. Never fence before the
//   dominant memory phase.
// R7 (baseline 66us): s_pj table + v_perm staging, proven.
// R8 (REGRESSED 131us): persistent for(;;) pipeline — WRITE_SIZE 94MB scratch
//   (spill sentinel), occupancy 35%. Dataflow CORRECT (absmax 0.5); codegen
//   collapsed. Lesson: no mega-loops.
// R9: same pipeline as straight-line 2-group unroll (grid=1024, no backedge):
//   stage(g1)+mlp(g1) overlap conv2-4(g0). Watch WRITE_SIZE==1024 for spill.

__device__ __forceinline__ float bf2f(unsigned short u) {
    return __uint_as_float(((unsigned int)u) << 16);
}
__device__ __forceinline__ unsigned short f2bf(float f) {
    unsigned int x = __float_as_uint(f);
    return (unsigned short)((x + 0x7fffu + ((x >> 16) & 1u)) >> 16);   // RNE
}
__device__ __forceinline__ void wsync() {
    __builtin_amdgcn_wave_barrier();
    __asm__ volatile("s_waitcnt lgkmcnt(0)" ::: "memory");
    __builtin_amdgcn_wave_barrier();
}

__device__ __forceinline__ bool is_bf16(const void* p, int elems) {
    const unsigned short* h = (const unsigned short*)p;
    int n = elems; if (n > 32) n = 32;
    int nz = 0, ok = 0;
    for (int i = 0; i < n; i += 2) {
        unsigned short u = h[i];
        if (u == 0) continue;
        ++nz;
        unsigned int e = (u >> 7) & 255u;
        if (e >= 100u && e <= 141u) ++ok;
    }
    if (nz < 4) return true;
    return 4 * ok >= 3 * nz;
}

__device__ __forceinline__ int wperm(int j) {
    if (j >= 30 && j < 192) {
        int rel = j - 30, c = rel / 27, r2 = rel - 27 * c;
        int tap = r2 / 3, ci = r2 - 3 * tap;
        return 30 + c * 27 + ci * 9 + tap;
    }
    if (j >= 198 && j < 360) {
        int rel = j - 198, c = rel / 54, r3 = rel - 54 * c;
        int tap = r3 / 6, ci = r3 - 6 * tap;
        return 198 + c * 54 + ci * 9 + tap;
    }
    return j;
}

// ---- phase helpers (bodies byte-identical to R8, which passed correctness) ----

__device__ __forceinline__ void do_stage(const void* image, float* SH, int B,
                                         int b0, int t, bool im_bf)
{
    unsigned short* su = (unsigned short*)SH;
    if (im_bf) {
        const unsigned short* im = (const unsigned short*)image;
        unsigned* sd = (unsigned*)SH;
        int d = t - 128;               // 0..383
        {
            const uint4 v0 = *(const uint4*)(im + (2 * d)     * B + b0);
            const uint4 v1 = *(const uint4*)(im + (2 * d + 1) * B + b0);
            unsigned a0[4] = {v0.x, v0.y, v0.z, v0.w};
            unsigned a1[4] = {v1.x, v1.y, v1.z, v1.w};
#pragma unroll
            for (int s = 0; s < 8; ++s) {
                unsigned m = __builtin_amdgcn_perm(
                    a1[s >> 1], a0[s >> 1],
                    (s & 1) ? 0x07060302u : 0x05040100u);
                sd[s * REG + d] = m;
            }
        }
        if (d < 8) {                   // dwords 384..391
            const int d2 = d + 384;
            const uint4 v0 = *(const uint4*)(im + (2 * d2)     * B + b0);
            const uint4 v1 = *(const uint4*)(im + (2 * d2 + 1) * B + b0);
            unsigned a0[4] = {v0.x, v0.y, v0.z, v0.w};
            unsigned a1[4] = {v1.x, v1.y, v1.z, v1.w};
#pragma unroll
            for (int s = 0; s < 8; ++s) {
                unsigned m = __builtin_amdgcn_perm(
                    a1[s >> 1], a0[s >> 1],
                    (s & 1) ? 0x07060302u : 0x05040100u);
                sd[s * REG + d2] = m;
            }
        }
    } else {
        const float* im = (const float*)image;
        int pix0 = t - 128;            // 0..383
        for (int pix = pix0; pix < 784; pix += 384) {
            const float4 a = *(const float4*)(im + pix * B + b0);
            const float4 c = *(const float4*)(im + pix * B + b0 + 4);
            su[0 * 2 * REG + pix] = f2bf(a.x);
            su[1 * 2 * REG + pix] = f2bf(a.y);
            su[2 * 2 * REG + pix] = f2bf(a.z);
            su[3 * 2 * REG + pix] = f2bf(a.w);
            su[4 * 2 * REG + pix] = f2bf(c.x);
            su[5 * 2 * REG + pix] = f2bf(c.y);
            su[6 * 2 * REG + pix] = f2bf(c.z);
            su[7 * 2 * REG + pix] = f2bf(c.w);
        }
    }
}

__device__ __forceinline__ void do_mlp(const void* state,
                                       const void* W1, const void* b1,
                                       const void* W2, const void* b2,
                                       float (*st)[16], float (*h1)[16], float (*h2)[16],
                                       int b0, int wv, int lane,
                                       bool st_bf, bool w1_bf, bool b1_bf,
                                       bool w2_bf, bool b2_bf)
{
    int s = wv * 4 + (lane >> 4), j = lane & 15;
    int gi = (b0 + s) * 16 + j;
    st[s][j] = st_bf ? bf2f(((const unsigned short*)state)[gi])
                     : ((const float*)state)[gi];
    wsync();
    float acc = b1_bf ? bf2f(((const unsigned short*)b1)[j])
                      : ((const float*)b1)[j];
#pragma unroll
    for (int k = 0; k < 16; ++k) {
        float w = w1_bf ? bf2f(((const unsigned short*)W1)[k * 16 + j])
                        : ((const float*)W1)[k * 16 + j];
        acc += st[s][k] * w;
    }
    h1[s][j] = fmaxf(acc, 0.f);
    wsync();
    acc = b2_bf ? bf2f(((const unsigned short*)b2)[j])
                : ((const float*)b2)[j];
#pragma unroll
    for (int k = 0; k < 16; ++k) {
        float w = w2_bf ? bf2f(((const unsigned short*)W2)[k * 16 + j])
                        : ((const float*)W2)[k * 16 + j];
        acc += h1[s][k] * w;
    }
    h2[s][j] = fmaxf(acc, 0.f);
}

__device__ __forceinline__ void do_head(const void* W3, const void* b3,
                                        float* SH, float (*h2)[16],
                                        const unsigned short* s_pj,
                                        int wv, int hn, int kg,
                                        bool w3_bf, bool b3_bf)
{
    bf16x8 afrag;
#pragma unroll
    for (int i = 0; i < 8; ++i) afrag[i] = 0;
    if (kg < 2 && hn < 8) {
        const int k0 = kg * 8;
#pragma unroll
        for (int i = 0; i < 8; ++i)
            afrag[i] = (short)f2bf(h2[hn][k0 + i]);
    }
    const unsigned short* b3h = (const unsigned short*)b3;
    const float*          b3f = (const float*)b3;
    for (int tile = wv; tile < 51; tile += 8) {
        const int jn = tile * 16 + hn;
        bf16x8 bfrag;
#pragma unroll
        for (int i = 0; i < 8; ++i) bfrag[i] = 0;
        if (kg < 2 && jn < 811) {
            const int k0 = kg * 8;
            if (w3_bf) {
                const unsigned short* q = (const unsigned short*)W3 + k0 * 811 + jn;
#pragma unroll
                for (int i = 0; i < 8; ++i) bfrag[i] = (short)q[i * 811];
            } else {
                const float* q = (const float*)W3 + k0 * 811 + jn;
#pragma unroll
                for (int i = 0; i < 8; ++i) bfrag[i] = (short)f2bf(q[i * 811]);
            }
        }
        f32x4 c = {0.f, 0.f, 0.f, 0.f};
        c = __builtin_amdgcn_mfma_f32_16x16x32_bf16(afrag, bfrag, c, 0, 0, 0);
        const int row0 = kg * 4;
        if (row0 < 8 && jn < 811) {
            float bb = b3_bf ? bf2f(b3h[jn]) : b3f[jn];
            const int pj = (int)s_pj[jn];
#pragma unroll
            for (int r = 0; r < 4; ++r)
                SH[(row0 + r) * REG + OFF_W + pj] = c[r] + bb;
        }
    }
}

__device__ __forceinline__ void do_conv1(float* SH, int wv, int lane)
{
    unsigned short* su = (unsigned short*)SH;
    const int sb  = wv * REG;
    const int sb2 = wv * 2 * REG;
    float wc[27], cb[3];
#pragma unroll
    for (int i = 0; i < 27; ++i) wc[i] = SH[sb + OFF_W + i];
#pragma unroll
    for (int c = 0; c < 3; ++c) cb[c] = SH[sb + OFF_W + 27 + c];
    const unsigned* suw = (const unsigned*)&SH[sb];
#pragma unroll
    for (int it = 0; it < 3; ++it) {
        int pix = lane + it * 64;
        if (pix < 169) {
            int py = pix / 13, px = pix - py * 13;
            int iy = 2 * py;
            f32x2 P[4][3];
#pragma unroll
            for (int dy = 0; dy < 4; ++dy) {
                int r = (iy + dy) * 14 + px;
                unsigned d0 = suw[r], d1 = suw[r + 1];
                float c0 = __uint_as_float(d0 << 16);
                float c1 = __uint_as_float(d0 & 0xffff0000u);
                float c2 = __uint_as_float(d1 << 16);
                float c3 = __uint_as_float(d1 & 0xffff0000u);
                P[dy][0] = (f32x2){c0, c1};
                P[dy][1] = (f32x2){c1, c2};
                P[dy][2] = (f32x2){c2, c3};
            }
            unsigned short* op = &su[sb2 + HW_P1 + py * 14 + px];
#pragma unroll
            for (int c = 0; c < 3; ++c) {
                f32x2 at = {0.f, 0.f}, ab = {0.f, 0.f};
#pragma unroll
                for (int ky = 0; ky < 3; ++ky)
#pragma unroll
                    for (int kx = 0; kx < 3; ++kx) {
                        float w = wc[c * 9 + ky * 3 + kx];
                        f32x2 ws = {w, w};
                        at += P[ky][kx]     * ws;
                        ab += P[ky + 1][kx] * ws;
                    }
                float m = fmaxf(fmaxf(at.x, at.y), fmaxf(ab.x, ab.y));
                op[c * 182] = f2bf(fmaxf(m + cb[c], 0.f));
            }
        }
    }
}

__device__ __forceinline__ void do_conv234(float* SH, float (*st)[16],
                                           void* out, int b0, int wv, int lane,
                                           bool out_bf)
{
    const int sb = wv * REG;

    // ---- conv2 (3->6 -> pool -> 5x5x6 fp32), ci-outer, C-packed ----
    {
        int gq = lane >> 5, q = lane & 31;
        if (q < 25) {
            int py = q / 5, px = q - py * 5;
            const unsigned* p1w = (const unsigned*)&SH[sb + DW_P1];
            f32x2 aT0 = {0.f,0.f}, aB0 = {0.f,0.f};
            f32x2 aT1 = {0.f,0.f}, aB1 = {0.f,0.f};
            f32x2 aT2 = {0.f,0.f}, aB2 = {0.f,0.f};
#pragma unroll
            for (int ci = 0; ci < 3; ++ci) {
                f32x2 P[4][3];
#pragma unroll
                for (int dy = 0; dy < 4; ++dy) {
                    int r = ci * 91 + (2 * py + dy) * 7 + px;
                    unsigned d0 = p1w[r], d1 = p1w[r + 1];
                    float c0 = __uint_as_float(d0 << 16);
                    float c1 = __uint_as_float(d0 & 0xffff0000u);
                    float c2 = __uint_as_float(d1 << 16);
                    float c3 = __uint_as_float(d1 & 0xffff0000u);
                    P[dy][0] = (f32x2){c0, c1};
                    P[dy][1] = (f32x2){c1, c2};
                    P[dy][2] = (f32x2){c2, c3};
                }
#pragma unroll
                for (int it = 0; it < 3; ++it) {
                    int c = it * 2 + gq;
                    const int wo = sb + OFF_W + 30 + c * 27 + ci * 9;
#pragma unroll
                    for (int ky = 0; ky < 3; ++ky)
#pragma unroll
                        for (int kx = 0; kx < 3; ++kx) {
                            float w = SH[wo + ky * 3 + kx];
                            f32x2 ws = {w, w};
                            if (it == 0) { aT0 += P[ky][kx] * ws; aB0 += P[ky+1][kx] * ws; }
                            if (it == 1) { aT1 += P[ky][kx] * ws; aB1 += P[ky+1][kx] * ws; }
                            if (it == 2) { aT2 += P[ky][kx] * ws; aB2 += P[ky+1][kx] * ws; }
                        }
                }
            }
#pragma unroll
            for (int it = 0; it < 3; ++it) {
                int c = it * 2 + gq;
                f32x2 aT = (it == 0) ? aT0 : (it == 1) ? aT1 : aT2;
                f32x2 aB = (it == 0) ? aB0 : (it == 1) ? aB1 : aB2;
                float m = fmaxf(fmaxf(aT.x, aT.y), fmaxf(aB.x, aB.y));
                SH[sb + DW_P2 + c * 25 + q] =
                    fmaxf(m + SH[sb + OFF_W + 192 + c], 0.f);
            }
        }
    }
    wsync();

    // ---- conv3 (6->3, 5x5 -> 3x3) + relu; P3 spatial-major in P1 tail ----
    {
        float acc = 0.f;
        int pq = lane % 27;
        int half = lane / 27;
        int c = pq / 9, pos = pq - c * 9;
        int py = pos / 3, px = pos - py * 3;
        if (lane < 54) {
            const int cb3 = half * 3;
#pragma unroll
            for (int ci3 = 0; ci3 < 3; ++ci3) {
                const int ci = cb3 + ci3;
                const int wo = sb + OFF_W + 198 + c * 54 + ci * 9;
                float wr[9];
#pragma unroll
                for (int i = 0; i < 9; ++i) wr[i] = SH[wo + i];
                const int pbase = sb + DW_P2 + ci * 25 + py * 5 + px;
#pragma unroll
                for (int ky = 0; ky < 3; ++ky)
#pragma unroll
                    for (int kx = 0; kx < 3; ++kx)
                        acc += SH[pbase + ky * 5 + kx] * wr[ky * 3 + kx];
            }
        }
        float other = __shfl(acc, (lane + 27) & 63);
        if (lane < 27)
            SH[sb + DW_P3 + pos * 3 + c] =
                fmaxf(acc + other + SH[sb + OFF_W + 360 + c], 0.f);
    }
    wsync();

    // ---- conv4 (3->16) + bias + residual -> out ----
    {
        float acc = 0.f;
        int os = lane & 15, h = (lane >> 4) & 1;
        if (lane < 32) {
            const int wo = sb + OFF_W + 363 + os * 27;
            int p0 = h ? 4 : 0, p1 = h ? 9 : 4;
            for (int pp = p0; pp < p1; ++pp)
#pragma unroll
                for (int ci = 0; ci < 3; ++ci)
                    acc += SH[sb + DW_P3 + pp * 3 + ci] * SH[wo + pp * 3 + ci];
        }
        float other = __shfl(acc, (lane + 16) & 63);
        if (lane < 16) {
            float tot = acc + other + SH[sb + OFF_W + 795 + os] + st[wv][os];
            int gi = (b0 + wv) * 16 + os;
            if (out_bf) ((unsigned short*)out)[gi] = f2bf(tot);
            else        ((float*)out)[gi] = tot;
        }
    }
}

// bound (512,4): VGPR cap 128; straight-line code keeps pressure ~48-64.
__global__ __launch_bounds__(BLK, 4)
void dyncnn4_kernel(const void* __restrict__ image,   // [784, B]
                    const void* __restrict__ state,   // [B, 16]
                    const void* __restrict__ W1, const void* __restrict__ b1,
                    const void* __restrict__ W2, const void* __restrict__ b2,
                    const void* __restrict__ W3, const void* __restrict__ b3,
                    void* __restrict__ out,           // [B,16]
                    int B, int ngrp, int nswz)
{
    __shared__ float SH[NSAMP * REG];     // 47360 B
    __shared__ float s_st0[NSAMP][16];
    __shared__ float s_st1[NSAMP][16];
    __shared__ float s_h1[NSAMP][16];
    __shared__ float s_h2[NSAMP][16];
    __shared__ unsigned char s_fl[8];
    __shared__ unsigned short s_pj[812];

    const int t    = threadIdx.x;
    const int wv   = t >> 6;
    const int lane = t & 63;
    const int hn   = lane & 15;
    const int kg   = lane >> 4;

    // ---- barrier #0: dtype flags + wperm table ----
    if (t < 8) {
        const void* q; int n;
        switch (t) {
            case 0:  q = image; n = 784 * B; break;
            case 1:  q = state; n = 16 * B;  break;
            case 2:  q = W1;    n = 256;     break;
            case 3:  q = b1;    n = 16;      break;
            case 4:  q = W2;    n = 256;     break;
            case 5:  q = b2;    n = 16;      break;
            case 6:  q = W3;    n = 12976;   break;
            default: q = b3;    n = 811;     break;
        }
        s_fl[t] = is_bf16(q, n) ? 1 : 0;
    }
    for (int j = t; j < 811; j += BLK)
        s_pj[j] = (unsigned short)wperm(j);
    __syncthreads();
    const bool im_bf = s_fl[0], st_bf = s_fl[1], w1_bf = s_fl[2], b1_bf = s_fl[3];
    const bool w2_bf = s_fl[4], b2_bf = s_fl[5], w3_bf = s_fl[6], b3_bf = s_fl[7];
    const bool out_bf = im_bf && st_bf && w1_bf && w2_bf && w3_bf;

    const int g0 = blockIdx.x;
    const int g1 = g0 + gridDim.x;
    const bool more = (g1 < ngrp);

    int lg0 = (nswz > 0) ? ((g0 & 7) * nswz + (g0 >> 3)) : g0;
    const int b0 = lg0 * NSAMP;
    int b1s = 0;
    if (more) {
        int lg1 = (nswz > 0) ? ((g1 & 7) * nswz + (g1 >> 3)) : g1;
        b1s = lg1 * NSAMP;
    }

    // ==== group 0: stage+mlp -> head -> conv1 ====
    if (wv < 2) do_mlp(state, W1, b1, W2, b2, s_st0, s_h1, s_h2, b0, wv, lane,
                       st_bf, w1_bf, b1_bf, w2_bf, b2_bf);
    else        do_stage(image, SH, B, b0, t, im_bf);
    __syncthreads();                      // #1: IMG(g0) + h2(g0) ready
    do_head(W3, b3, SH, s_h2, s_pj, wv, hn, kg, w3_bf, b3_bf);
    __syncthreads();                      // #2: W(g0) ready
    do_conv1(SH, wv, lane);
    __syncthreads();                      // #3 (barA): IMG(g0) fully consumed

    // ==== overlap: stage(g1)+mlp(g1) issue first, conv2-4(g0) computes ====
    if (more) {
        if (wv < 2) do_mlp(state, W1, b1, W2, b2, s_st1, s_h1, s_h2, b1s, wv, lane,
                           st_bf, w1_bf, b1_bf, w2_bf, b2_bf);
        else        do_stage(image, SH, B, b1s, t, im_bf);
    }
    do_conv234(SH, s_st0, out, b0, wv, lane, out_bf);
    __syncthreads();                      // #4 (barB): convs(g0) + stage/mlp(g1) done

    if (!more) return;

    // ==== group 1: head -> conv1 -> conv2-4 ====
    do_head(W3, b3, SH, s_h2, s_pj, wv, hn, kg, w3_bf, b3_bf);
    __syncthreads();                      // #5: W(g1) ready
    do_conv1(SH, wv, lane);
    wsync();
    do_conv234(SH, s_st1, out, b1s, wv, lane, out_bf);
}

extern "C" void kernel_launch(void* const* d_in, const int* in_sizes, int n_in,
                              void* d_out, int out_size, void* d_ws, size_t ws_size,
                              hipStream_t stream) {
    (void)d_ws; (void)ws_size; (void)n_in; (void)out_size;
    int B = in_sizes[1] / 16;              // 16384
    int ngrp = B / NSAMP;                  // 2048
    int nswz = (ngrp % 8 == 0) ? (ngrp / 8) : 0;
    int grid = (ngrp + 1) / 2;             // 2 groups per block

    dyncnn4_kernel<<<grid, BLK, 0, stream>>>(
        d_in[0], d_in[1], d_in[2], d_in[3], d_in[4], d_in[5], d_in[6], d_in[7],
        d_out, B, ngrp, nswz);
}

// Round 10
// 139.270 us; speedup vs baseline: 1.3258x; 1.0436x over previous
//
#include <hip/hip_runtime.h>

#define BLK   512
#define NSAMP 8
#define REG   1480          // dwords per sample LDS region (5920 B)
// per-sample region map:
//  IMG:  halfwords [0..783] = dw [0..391] (bf16; dead after conv1)
//  P2:   dw [0..149]   (5x5x6 fp32, c*25+pos)   -- aliases dead IMG
//  P3:   dw [152..178] (3x3x3 fp32, SPATIAL-major pos*3+c)  -- aliases dead IMG
//  W:    dw [392..1203] (811 hypernet weights, fp32, PERMUTED — see below)
//  P1:   halfwords [2408..2953] = dw [1204..1476] (3ch * 13rows * stride14, bf16)
#define OFF_P2   0          // dw
#define OFF_P3   152        // dw
#define OFF_W    392        // dw
#define HW_P1    2408       // halfword offset of P1
#define DW_P1    1204       // dword offset of P1

// W section layout (PERMUTED at head-write time so conv reads are contiguous):
//  w1 [0,27)   : [c][tap]      b1 [27,30)
//  w2 [30,192) : [c][ci][tap]  b2 [192,198)
//  w3 [198,360): [c][ci][tap]  b3 [360,363)
//  w4 [363,795): [c][tap][ci]  b4 [795,811)

typedef short bf16x8 __attribute__((ext_vector_type(8)));
typedef float f32x4  __attribute__((ext_vector_type(4)));
typedef float f32x2  __attribute__((ext_vector_type(2)));

// Journal (final ledger):
// R1: asm v_pk_fma op_sel broadcast FAILED correctness. Never again.
// R2 (WIN 78->65us): C float2 packed math — compiler emits v_pk_fma, exact.
// R3 (REGRESSED 65->82): bf16 W in LDS -> merge-proof ds_read_u16; occupancy
//   (3 vs 4 blocks/CU) proven NOT binding.
// R5 (NEUTRAL): W3 reg-prefetch sunk by compiler.
// R6 (REGRESSED 65->79): pinning prefetch fenced the staging loads — never
//   fence before the dominant memory phase.
// R7 (BEST, 65.4-66.9us): s_pj table + v_perm staging, proven correct.
// R8 (REGRESSED 131us): persistent for(;;) pipeline -> spill (WRITE 94MB).
// R9 (REGRESSED 70-74us): clean 2-group unroll pipeline -> occupancy 38%
//   (drain tail doubled). CONCLUSION: inter-block TLP already hides phase
//   latency; intra-block overlap buys nothing. This structure's floor ~66us.

__device__ __forceinline__ float bf2f(unsigned short u) {
    return __uint_as_float(((unsigned int)u) << 16);
}
__device__ __forceinline__ unsigned short f2bf(float f) {
    unsigned int x = __float_as_uint(f);
    return (unsigned short)((x + 0x7fffu + ((x >> 16) & 1u)) >> 16);   // RNE
}
__device__ __forceinline__ void wsync() {
    __builtin_amdgcn_wave_barrier();
    __asm__ volatile("s_waitcnt lgkmcnt(0)" ::: "memory");
    __builtin_amdgcn_wave_barrier();
}

// Runtime dtype detection: probe EVEN halfwords.
__device__ __forceinline__ bool is_bf16(const void* p, int elems) {
    const unsigned short* h = (const unsigned short*)p;
    int n = elems; if (n > 32) n = 32;
    int nz = 0, ok = 0;
    for (int i = 0; i < n; i += 2) {
        unsigned short u = h[i];
        if (u == 0) continue;
        ++nz;
        unsigned int e = (u >> 7) & 255u;
        if (e >= 100u && e <= 141u) ++ok;
    }
    if (nz < 4) return true;
    return 4 * ok >= 3 * nz;
}

// head-write permutation: logical j -> stored index
__device__ __forceinline__ int wperm(int j) {
    if (j >= 30 && j < 192) {
        int rel = j - 30, c = rel / 27, r2 = rel - 27 * c;
        int tap = r2 / 3, ci = r2 - 3 * tap;
        return 30 + c * 27 + ci * 9 + tap;
    }
    if (j >= 198 && j < 360) {
        int rel = j - 198, c = rel / 54, r3 = rel - 54 * c;
        int tap = r3 / 6, ci = r3 - 6 * tap;
        return 198 + c * 54 + ci * 9 + tap;
    }
    return j;
}

// bound (512,4): VGPR cap 128. NO runtime-indexed ext_vector arrays (scratch trap).
__global__ __launch_bounds__(BLK, 4)
void dyncnn4_kernel(const void* __restrict__ image,   // [784, B]
                    const void* __restrict__ state,   // [B, 16]
                    const void* __restrict__ W1, const void* __restrict__ b1,
                    const void* __restrict__ W2, const void* __restrict__ b2,
                    const void* __restrict__ W3, const void* __restrict__ b3,
                    void* __restrict__ out,           // [B,16]
                    int B, int nswz)
{
    __shared__ float SH[NSAMP * REG];     // 47360 B
    __shared__ float s_st[NSAMP][16];
    __shared__ float s_h1[NSAMP][16];
    __shared__ float s_h2[NSAMP][16];
    __shared__ unsigned char s_fl[8];
    __shared__ unsigned short s_pj[812];  // wperm lookup

    const int t    = threadIdx.x;
    const int wv   = t >> 6;     // 0..7
    const int lane = t & 63;
    const int hn   = lane & 15;  // head: output column
    const int kg   = lane >> 4;  // head: k-group 0..3 (kg>=2 -> zero pad)

    // ---- barrier #0: dtype flags + wperm table ----
    if (t < 8) {
        const void* q; int n;
        switch (t) {
            case 0:  q = image; n = 784 * B; break;
            case 1:  q = state; n = 16 * B;  break;
            case 2:  q = W1;    n = 256;     break;
            case 3:  q = b1;    n = 16;      break;
            case 4:  q = W2;    n = 256;     break;
            case 5:  q = b2;    n = 16;      break;
            case 6:  q = W3;    n = 12976;   break;
            default: q = b3;    n = 811;     break;
        }
        s_fl[t] = is_bf16(q, n) ? 1 : 0;
    }
    for (int j = t; j < 811; j += BLK)
        s_pj[j] = (unsigned short)wperm(j);
    __syncthreads();
    const bool im_bf = s_fl[0], st_bf = s_fl[1], w1_bf = s_fl[2], b1_bf = s_fl[3];
    const bool w2_bf = s_fl[4], b2_bf = s_fl[5], w3_bf = s_fl[6], b3_bf = s_fl[7];
    const bool out_bf = im_bf && st_bf && w1_bf && w2_bf && w3_bf;

    int p = blockIdx.x;
    int l = (nswz > 0) ? ((p & 7) * nswz + (p >> 3)) : p;
    const int b0 = l * NSAMP;

    unsigned short* su = (unsigned short*)SH;   // halfword view

    // ==== prefetch (unpinned — compiler may sink; proven neutral) ====
    bf16x8 bp0 = {0,0,0,0,0,0,0,0}, bp1 = {0,0,0,0,0,0,0,0}, bp2 = {0,0,0,0,0,0,0,0},
           bp3 = {0,0,0,0,0,0,0,0}, bp4 = {0,0,0,0,0,0,0,0}, bp5 = {0,0,0,0,0,0,0,0},
           bp6 = {0,0,0,0,0,0,0,0};
    if (w3_bf) {
        const unsigned short* W3h = (const unsigned short*)W3;
#define PREF(T, BP) { const int tl = wv + (T) * 8; const int jn = tl * 16 + hn;      \
        if (kg < 2 && tl < 51 && jn < 811) {                                          \
            const unsigned short* q = W3h + (kg * 8) * 811 + jn;                      \
            BP[0] = (short)q[0];      BP[1] = (short)q[811];                          \
            BP[2] = (short)q[1622];   BP[3] = (short)q[2433];                         \
            BP[4] = (short)q[3244];   BP[5] = (short)q[4055];                         \
            BP[6] = (short)q[4866];   BP[7] = (short)q[5677]; } }
        PREF(0, bp0) PREF(1, bp1) PREF(2, bp2) PREF(3, bp3)
        PREF(4, bp4) PREF(5, bp5) PREF(6, bp6)
#undef PREF
    }

    // ==== phase 0: waves0-1 = MLP (4 samples each), waves2-7 = image staging ====
    if (wv < 2) {
        int s = wv * 4 + (lane >> 4), j = lane & 15;
        int gi = (b0 + s) * 16 + j;
        s_st[s][j] = st_bf ? bf2f(((const unsigned short*)state)[gi])
                           : ((const float*)state)[gi];
        wsync();
        float acc = b1_bf ? bf2f(((const unsigned short*)b1)[j])
                          : ((const float*)b1)[j];
#pragma unroll
        for (int k = 0; k < 16; ++k) {
            float w = w1_bf ? bf2f(((const unsigned short*)W1)[k * 16 + j])
                            : ((const float*)W1)[k * 16 + j];
            acc += s_st[s][k] * w;
        }
        s_h1[s][j] = fmaxf(acc, 0.f);
        wsync();
        acc = b2_bf ? bf2f(((const unsigned short*)b2)[j])
                    : ((const float*)b2)[j];
#pragma unroll
        for (int k = 0; k < 16; ++k) {
            float w = w2_bf ? bf2f(((const unsigned short*)W2)[k * 16 + j])
                            : ((const float*)W2)[k * 16 + j];
            acc += s_h1[s][k] * w;
        }
        s_h2[s][j] = fmaxf(acc, 0.f);
    } else {
        if (im_bf) {
            // v_perm staging: thread owns pixel PAIR (2d, 2d+1); one ds_write_b32
            // per sample. sel 0x05040100 = {b.hw0, a.hw0}; 0x07060302 = {b.hw1, a.hw1}.
            const unsigned short* im = (const unsigned short*)image;
            unsigned* sd = (unsigned*)SH;
            int d = t - 128;               // 0..383
            {
                const uint4 v0 = *(const uint4*)(im + (2 * d)     * B + b0);
                const uint4 v1 = *(const uint4*)(im + (2 * d + 1) * B + b0);
                unsigned a0[4] = {v0.x, v0.y, v0.z, v0.w};
                unsigned a1[4] = {v1.x, v1.y, v1.z, v1.w};
#pragma unroll
                for (int s = 0; s < 8; ++s) {
                    unsigned m = __builtin_amdgcn_perm(
                        a1[s >> 1], a0[s >> 1],
                        (s & 1) ? 0x07060302u : 0x05040100u);
                    sd[s * REG + d] = m;
                }
            }
            if (d < 8) {                   // dwords 384..391
                const int d2 = d + 384;
                const uint4 v0 = *(const uint4*)(im + (2 * d2)     * B + b0);
                const uint4 v1 = *(const uint4*)(im + (2 * d2 + 1) * B + b0);
                unsigned a0[4] = {v0.x, v0.y, v0.z, v0.w};
                unsigned a1[4] = {v1.x, v1.y, v1.z, v1.w};
#pragma unroll
                for (int s = 0; s < 8; ++s) {
                    unsigned m = __builtin_amdgcn_perm(
                        a1[s >> 1], a0[s >> 1],
                        (s & 1) ? 0x07060302u : 0x05040100u);
                    sd[s * REG + d2] = m;
                }
            }
        } else {
            const float* im = (const float*)image;
            int pix0 = t - 128;            // 0..383
            for (int pix = pix0; pix < 784; pix += 384) {
                const float4 a = *(const float4*)(im + pix * B + b0);
                const float4 c = *(const float4*)(im + pix * B + b0 + 4);
                su[0 * 2 * REG + pix] = f2bf(a.x);
                su[1 * 2 * REG + pix] = f2bf(a.y);
                su[2 * 2 * REG + pix] = f2bf(a.z);
                su[3 * 2 * REG + pix] = f2bf(a.w);
                su[4 * 2 * REG + pix] = f2bf(c.x);
                su[5 * 2 * REG + pix] = f2bf(c.y);
                su[6 * 2 * REG + pix] = f2bf(c.z);
                su[7 * 2 * REG + pix] = f2bf(c.w);
            }
        }
    }
    __syncthreads();   // barrier #1: image staged + h2 ready

    // ==== head via MFMA: w[8][811] = h2[8][16] @ W3[16][811] + b3 ====
    {
        bf16x8 afrag;
#pragma unroll
        for (int i = 0; i < 8; ++i) afrag[i] = 0;
        if (kg < 2 && hn < 8) {
            const int k0 = kg * 8;
#pragma unroll
            for (int i = 0; i < 8; ++i)
                afrag[i] = (short)f2bf(s_h2[hn][k0 + i]);
        }
        const unsigned short* b3h = (const unsigned short*)b3;
        const float*          b3f = (const float*)b3;
        if (w3_bf) {
#define HTILE(T, BP) { const int tl = wv + (T) * 8; const int jn = tl * 16 + hn;     \
            f32x4 c = {0.f, 0.f, 0.f, 0.f};                                           \
            c = __builtin_amdgcn_mfma_f32_16x16x32_bf16(afrag, BP, c, 0, 0, 0);       \
            const int row0 = kg * 4;                                                  \
            if (tl < 51 && row0 < 8 && jn < 811) {                                    \
                float bb = b3_bf ? bf2f(b3h[jn]) : b3f[jn];                            \
                const int pj = (int)s_pj[jn];                                         \
                SH[(row0 + 0) * REG + OFF_W + pj] = c[0] + bb;                        \
                SH[(row0 + 1) * REG + OFF_W + pj] = c[1] + bb;                        \
                SH[(row0 + 2) * REG + OFF_W + pj] = c[2] + bb;                        \
                SH[(row0 + 3) * REG + OFF_W + pj] = c[3] + bb; } }
            HTILE(0, bp0) HTILE(1, bp1) HTILE(2, bp2) HTILE(3, bp3)
            HTILE(4, bp4) HTILE(5, bp5) HTILE(6, bp6)
#undef HTILE
        } else {
            for (int tile = wv; tile < 51; tile += 8) {
                const int jn = tile * 16 + hn;
                bf16x8 bfrag;
#pragma unroll
                for (int i = 0; i < 8; ++i) bfrag[i] = 0;
                if (kg < 2 && jn < 811) {
                    const int k0 = kg * 8;
                    const float* q = (const float*)W3 + k0 * 811 + jn;
#pragma unroll
                    for (int i = 0; i < 8; ++i) bfrag[i] = (short)f2bf(q[i * 811]);
                }
                f32x4 c = {0.f, 0.f, 0.f, 0.f};
                c = __builtin_amdgcn_mfma_f32_16x16x32_bf16(afrag, bfrag, c, 0, 0, 0);
                const int row0 = kg * 4;
                if (row0 < 8 && jn < 811) {
                    float bb = b3_bf ? bf2f(b3h[jn]) : b3f[jn];
                    const int pj = (int)s_pj[jn];
#pragma unroll
                    for (int r = 0; r < 4; ++r)
                        SH[(row0 + r) * REG + OFF_W + pj] = c[r] + bb;
                }
            }
        }
    }
    __syncthreads();   // barrier #2: weights ready — conv phase is wave-local

    // ==== per-wave CNN: wave wv owns sample b0+wv ====
    const int sb  = wv * REG;        // dword base
    const int sb2 = wv * 2 * REG;    // halfword base

    // ---- conv1 (1->3, 28x28 -> fused pool -> 13x13x3 bf16), C-packed f32 ----
    {
        float wc[27], cb[3];
#pragma unroll
        for (int i = 0; i < 27; ++i) wc[i] = SH[sb + OFF_W + i];
#pragma unroll
        for (int c = 0; c < 3; ++c) cb[c] = SH[sb + OFF_W + 27 + c];
        const unsigned* suw = (const unsigned*)&SH[sb];  // 2 pixels per dword
#pragma unroll
        for (int it = 0; it < 3; ++it) {
            int pix = lane + it * 64;
            if (pix < 169) {
                int py = pix / 13, px = pix - py * 13;
                int iy = 2 * py;
                f32x2 P[4][3];
#pragma unroll
                for (int dy = 0; dy < 4; ++dy) {
                    int r = (iy + dy) * 14 + px;
                    unsigned d0 = suw[r], d1 = suw[r + 1];
                    float c0 = __uint_as_float(d0 << 16);
                    float c1 = __uint_as_float(d0 & 0xffff0000u);
                    float c2 = __uint_as_float(d1 << 16);
                    float c3 = __uint_as_float(d1 & 0xffff0000u);
                    P[dy][0] = (f32x2){c0, c1};
                    P[dy][1] = (f32x2){c1, c2};
                    P[dy][2] = (f32x2){c2, c3};
                }
                unsigned short* op = &su[sb2 + HW_P1 + py * 14 + px];
#pragma unroll
                for (int c = 0; c < 3; ++c) {
                    f32x2 at = {0.f, 0.f}, ab = {0.f, 0.f};
#pragma unroll
                    for (int ky = 0; ky < 3; ++ky)
#pragma unroll
                        for (int kx = 0; kx < 3; ++kx) {
                            float w = wc[c * 9 + ky * 3 + kx];
                            f32x2 ws = {w, w};
                            at += P[ky][kx]     * ws;
                            ab += P[ky + 1][kx] * ws;
                        }
                    float m = fmaxf(fmaxf(at.x, at.y), fmaxf(ab.x, ab.y));
                    op[c * 182] = f2bf(fmaxf(m + cb[c], 0.f));
                }
            }
        }
    }
    wsync();

    // ---- conv2 (3->6, 13x13 -> fused pool -> 5x5x6 fp32), ci-outer, C-packed ----
    {
        int g = lane >> 5, q = lane & 31;
        if (q < 25) {
            int py = q / 5, px = q - py * 5;
            const unsigned* p1w = (const unsigned*)&SH[sb + DW_P1];
            f32x2 aT0 = {0.f, 0.f}, aB0 = {0.f, 0.f};
            f32x2 aT1 = {0.f, 0.f}, aB1 = {0.f, 0.f};
            f32x2 aT2 = {0.f, 0.f}, aB2 = {0.f, 0.f};
#pragma unroll
            for (int ci = 0; ci < 3; ++ci) {
                f32x2 P[4][3];
#pragma unroll
                for (int dy = 0; dy < 4; ++dy) {
                    int r = ci * 91 + (2 * py + dy) * 7 + px;
                    unsigned d0 = p1w[r], d1 = p1w[r + 1];
                    float c0 = __uint_as_float(d0 << 16);
                    float c1 = __uint_as_float(d0 & 0xffff0000u);
                    float c2 = __uint_as_float(d1 << 16);
                    float c3 = __uint_as_float(d1 & 0xffff0000u);
                    P[dy][0] = (f32x2){c0, c1};
                    P[dy][1] = (f32x2){c1, c2};
                    P[dy][2] = (f32x2){c2, c3};
                }
#pragma unroll
                for (int it = 0; it < 3; ++it) {
                    int c = it * 2 + g;
                    const int wo = sb + OFF_W + 30 + c * 27 + ci * 9;
#pragma unroll
                    for (int ky = 0; ky < 3; ++ky)
#pragma unroll
                        for (int kx = 0; kx < 3; ++kx) {
                            float w = SH[wo + ky * 3 + kx];
                            f32x2 ws = {w, w};
                            if (it == 0) { aT0 += P[ky][kx] * ws; aB0 += P[ky + 1][kx] * ws; }
                            if (it == 1) { aT1 += P[ky][kx] * ws; aB1 += P[ky + 1][kx] * ws; }
                            if (it == 2) { aT2 += P[ky][kx] * ws; aB2 += P[ky + 1][kx] * ws; }
                        }
                }
            }
#pragma unroll
            for (int it = 0; it < 3; ++it) {
                int c = it * 2 + g;
                f32x2 aT = (it == 0) ? aT0 : (it == 1) ? aT1 : aT2;
                f32x2 aB = (it == 0) ? aB0 : (it == 1) ? aB1 : aB2;
                float m = fmaxf(fmaxf(aT.x, aT.y), fmaxf(aB.x, aB.y));
                SH[sb + OFF_P2 + c * 25 + q] =
                    fmaxf(m + SH[sb + OFF_W + 192 + c], 0.f);
            }
        }
    }
    wsync();

    // ---- conv3 (6->3, 5x5 -> 3x3) + relu, 54-lane split over ci halves ----
    {
        float acc = 0.f;
        int pq = lane % 27;            // 0..26: c*9 + pos
        int half = lane / 27;          // 0,1 active; lane>=54 idle
        int c = pq / 9, pos = pq - c * 9;
        int py = pos / 3, px = pos - py * 3;
        if (lane < 54) {
            const int cb3 = half * 3;
#pragma unroll
            for (int ci3 = 0; ci3 < 3; ++ci3) {
                const int ci = cb3 + ci3;
                const int wo = sb + OFF_W + 198 + c * 54 + ci * 9;
                float wr[9];
#pragma unroll
                for (int i = 0; i < 9; ++i) wr[i] = SH[wo + i];
                const int pbase = sb + OFF_P2 + ci * 25 + py * 5 + px;
#pragma unroll
                for (int ky = 0; ky < 3; ++ky)
#pragma unroll
                    for (int kx = 0; kx < 3; ++kx)
                        acc += SH[pbase + ky * 5 + kx] * wr[ky * 3 + kx];
            }
        }
        float other = __shfl(acc, (lane + 27) & 63);
        if (lane < 27)
            SH[sb + OFF_P3 + pos * 3 + c] =
                fmaxf(acc + other + SH[sb + OFF_W + 360 + c], 0.f);
    }
    wsync();

    // ---- conv4 (3->16) + bias + residual -> out, 32-lane split over pp ----
    {
        float acc = 0.f;
        int os = lane & 15, h = (lane >> 4) & 1;
        if (lane < 32) {
            const int wo = sb + OFF_W + 363 + os * 27;
            int p0 = h ? 4 : 0, p1 = h ? 9 : 4;
            for (int pp = p0; pp < p1; ++pp)
#pragma unroll
                for (int ci = 0; ci < 3; ++ci)
                    acc += SH[sb + OFF_P3 + pp * 3 + ci] * SH[wo + pp * 3 + ci];
        }
        float other = __shfl(acc, (lane + 16) & 63);
        if (lane < 16) {
            float tot = acc + other + SH[sb + OFF_W + 795 + os] + s_st[wv][os];
            int gi = (b0 + wv) * 16 + os;
            if (out_bf) ((unsigned short*)out)[gi] = f2bf(tot);
            else        ((float*)out)[gi] = tot;
        }
    }
}

extern "C" void kernel_launch(void* const* d_in, const int* in_sizes, int n_in,
                              void* d_out, int out_size, void* d_ws, size_t ws_size,
                              hipStream_t stream) {
    (void)d_ws; (void)ws_size; (void)n_in; (void)out_size;
    int B = in_sizes[1] / 16;              // 16384
    int nblocks = B / NSAMP;               // 2048
    int nswz = (nblocks % 8 == 0) ? (nblocks / 8) : 0;

    dyncnn4_kernel<<<nblocks, BLK, 0, stream>>>(
        d_in[0], d_in[1], d_in[2], d_in[3], d_in[4], d_in[5], d_in[6], d_in[7],
        d_out, B, nswz);
}